// Round 3
// baseline (2657.008 us; speedup 1.0000x reference)
//
#include <hip/hip_runtime.h>
#include <math.h>

#define T 4
#define HH 64
#define HE 16
#define HD 128
#define EPSF 1e-8f

#define TE 16                     // edges per block
#define ROWS 64                   // TE*T merged rows
#define LDA 168     // k-stride bf16 elems for K=160 buf: 336B = 84 banks == 20 mod 32
#define LDB 136     // K=128 activation buf: 272B = 68 banks == 4 mod 32
#define TN 16       // nodes per block
#define LDAN 200    // K=192 buf: 400B == 4 mod 32

using frag8 = __attribute__((ext_vector_type(8))) short;
using f32x4 = __attribute__((ext_vector_type(4))) float;

__device__ __forceinline__ float silu_f(float v) { return v / (1.f + __expf(-v)); }

__device__ __forceinline__ unsigned short f2b(float f) {
    union { float f; unsigned u; } v; v.f = f;
    unsigned r = v.u + 0x7FFF + ((v.u >> 16) & 1);   // RNE
    return (unsigned short)(r >> 16);
}
__device__ __forceinline__ unsigned pk2(float a, float b) {
    return (unsigned)f2b(a) | ((unsigned)f2b(b) << 16);
}
__device__ __forceinline__ uint4 pk8(const float* v) {
    uint4 r;
    r.x = pk2(v[0], v[1]); r.y = pk2(v[2], v[3]);
    r.z = pk2(v[4], v[5]); r.w = pk2(v[6], v[7]);
    return r;
}

// ---------------- weight prep: fp32 -> bf16, transposed to [n][k] ----------------
// wb layout (bf16 elems): w1b [128][160] @0 (k: 0..127 h_row|h_col, 128..143 ea, 144 n2)
//                         w2b [128][128] @20480, cw1b [128][128] @36864,
//                         nw1b [128][192] @53248, nw2b [64][128] @77824   (total 86016)
__global__ void prep_weights(const float* __restrict__ w1, const float* __restrict__ w2,
                             const float* __restrict__ cw1, const float* __restrict__ nw1,
                             const float* __restrict__ nw2, unsigned short* __restrict__ wb)
{
    int i = blockIdx.x * 256 + threadIdx.x;
    if (i < 20480) {
        int n = i / 160, k = i - n * 160;
        float v;
        if (k < 128)      v = w1[k * 128 + n];
        else if (k < 144) v = w1[(129 + (k - 128)) * 128 + n];   // ea dims
        else if (k == 144) v = w1[128 * 128 + n];                 // n2 dim
        else              v = 0.f;
        wb[i] = f2b(v);
    } else if (i < 36864) {
        int j = i - 20480; int n = j >> 7, k = j & 127;
        wb[i] = f2b(w2[k * 128 + n]);
    } else if (i < 53248) {
        int j = i - 36864; int n = j >> 7, k = j & 127;
        wb[i] = f2b(cw1[k * 128 + n]);
    } else if (i < 77824) {
        int j = i - 53248; int n = j / 192, k = j - n * 192;
        wb[i] = f2b(nw1[k * 128 + n]);
    } else if (i < 86016) {
        int j = i - 77824; int n = j >> 7, k = j & 127;
        wb[i] = f2b(nw2[k * 64 + n]);
    }
}

// ---------------- edge kernel: 16 edges (64 rows), 256 threads, ~40 KB LDS ----------------
__global__ __launch_bounds__(256, 4)
void edge_kernel(const float* __restrict__ x, const float* __restrict__ h,
                 const int* __restrict__ ei, const float* __restrict__ ea,
                 const unsigned short* __restrict__ w1b,
                 const unsigned short* __restrict__ w2b,
                 const unsigned short* __restrict__ cw1b,
                 const float* __restrict__ b1, const float* __restrict__ b2,
                 const float* __restrict__ cb1, const float* __restrict__ cb2,
                 const float* __restrict__ cw2,
                 float* __restrict__ m_i, float* __restrict__ agg, float* __restrict__ cnt,
                 int N, int E)
{
    __shared__ unsigned short sA[ROWS * LDA];   // m_in (K=160), later y2 (K=128)
    __shared__ unsigned short sB[ROWS * LDB];   // y1 / c1
    __shared__ float sXij[TE * 12];
    __shared__ float sNorm[ROWS];
    __shared__ int   sNode[TE];

    const int tid = threadIdx.x;
    const int e0  = blockIdx.x * TE;

    if (tid < TE) {
        int e = e0 + tid;
        sNode[tid] = (e < E) ? ei[e] : 0;
    }
    if (tid >= TE && tid < TE + TE * 12) {
        int j = tid - TE;
        int le = j / 12, i = j - le * 12;     // i = axis*4 + t
        int e = e0 + le;
        float d = 0.f;
        if (e < E) { int rn = ei[e], cn = ei[E + e]; d = x[rn * 12 + i] - x[cn * 12 + i]; }
        sXij[j] = d;
    }
    // h gather: 16 le x 2 half x 8 d0 = 256 assignments, 128B contiguous each
    {
        int half = tid >> 7;
        int t7 = tid & 127;
        int le = t7 >> 3, d0 = (t7 & 7) * 8;
        int e = e0 + le;
        if (e < E) {
            int node = ei[half ? (E + e) : e];
            const float4* hp = (const float4*)(h + (size_t)node * 256);
            float4 hv[8];
            #pragma unroll
            for (int q = 0; q < 8; ++q) hv[q] = hp[d0 + q];
            #pragma unroll
            for (int t = 0; t < 4; ++t) {
                float vv[8];
                #pragma unroll
                for (int q = 0; q < 8; ++q) vv[q] = ((const float*)&hv[q])[t];
                *(uint4*)&sA[(le * 4 + t) * LDA + half * 64 + d0] = pk8(vv);
            }
        }
    }
    // edge_attr: k 128..143  (16 le x 4 chunks = 64 assignments)
    if (tid < 64) {
        int le = tid >> 2, eh0 = (tid & 3) * 4;
        int e = e0 + le;
        if (e < E) {
            const float4* ap = (const float4*)(ea + (size_t)e * 64);
            float4 av[4];
            #pragma unroll
            for (int q = 0; q < 4; ++q) av[q] = ap[eh0 + q];
            #pragma unroll
            for (int t = 0; t < 4; ++t) {
                uint2 u;
                u.x = pk2(((const float*)&av[0])[t], ((const float*)&av[1])[t]);
                u.y = pk2(((const float*)&av[2])[t], ((const float*)&av[3])[t]);
                *(uint2*)&sA[(le * 4 + t) * LDA + 128 + eh0] = u;
            }
        }
    }
    __syncthreads();
    // n2 at k=144, zero-pad k 145..159
    if (tid < ROWS) {
        int le = tid >> 2, t = tid & 3;
        float a0 = sXij[le * 12 + t], a1 = sXij[le * 12 + 4 + t], a2 = sXij[le * 12 + 8 + t];
        float n2 = a0 * a0 + a1 * a1 + a2 * a2;
        sNorm[tid] = n2;
        uint4 z = {0, 0, 0, 0};
        *(uint4*)&sA[tid * LDA + 144] = z;
        *(uint4*)&sA[tid * LDA + 152] = z;
        sA[tid * LDA + 144] = f2b(n2);
    }
    __syncthreads();

    const int lane = tid & 63;
    const int wave = tid >> 6;
    const int lrow = lane & 15;
    const int quad = lane >> 4;
    const int mbase = wave * 16;

    // ---- layer 1: [64 x 160] @ [160 x 128], B direct from global (L2) ----
    f32x4 acc[8];
    #pragma unroll
    for (int nt = 0; nt < 8; ++nt) acc[nt] = (f32x4){0.f, 0.f, 0.f, 0.f};
    #pragma unroll
    for (int kb = 0; kb < 5; ++kb) {
        frag8 a = *(const frag8*)&sA[(mbase + lrow) * LDA + kb * 32 + quad * 8];
        #pragma unroll
        for (int nt = 0; nt < 8; ++nt) {
            frag8 b = *(const frag8*)&w1b[(nt * 16 + lrow) * 160 + kb * 32 + quad * 8];
            acc[nt] = __builtin_amdgcn_mfma_f32_16x16x32_bf16(a, b, acc[nt], 0, 0, 0);
        }
    }
    #pragma unroll
    for (int nt = 0; nt < 8; ++nt) {
        int col = nt * 16 + lrow;
        float bias = b1[col];
        #pragma unroll
        for (int r = 0; r < 4; ++r)
            sB[(mbase + quad * 4 + r) * LDB + col] = f2b(silu_f(acc[nt][r] + bias));
    }
    __syncthreads();

    // ---- layer 2: y2 = silu(y1 @ w2 + b2) + m_i atomics ----
    #pragma unroll
    for (int nt = 0; nt < 8; ++nt) acc[nt] = (f32x4){0.f, 0.f, 0.f, 0.f};
    #pragma unroll
    for (int kb = 0; kb < 4; ++kb) {
        frag8 a = *(const frag8*)&sB[(mbase + lrow) * LDB + kb * 32 + quad * 8];
        #pragma unroll
        for (int nt = 0; nt < 8; ++nt) {
            frag8 b = *(const frag8*)&w2b[(nt * 16 + lrow) * 128 + kb * 32 + quad * 8];
            acc[nt] = __builtin_amdgcn_mfma_f32_16x16x32_bf16(a, b, acc[nt], 0, 0, 0);
        }
    }
    {
        int le = wave * 4 + quad;            // C row = mbase + quad*4 + r -> edge le, t=r
        int e = e0 + le;
        bool valid = e < E;
        int node = sNode[le];
        float* mb = m_i + (size_t)node * 512;
        #pragma unroll
        for (int nt = 0; nt < 8; ++nt) {
            int col = nt * 16 + lrow;
            float bias = b2[col];
            #pragma unroll
            for (int r = 0; r < 4; ++r) {
                float v = silu_f(acc[nt][r] + bias);
                sA[(mbase + quad * 4 + r) * LDA + col] = f2b(v);
                if (valid) atomicAdd(mb + col * 4 + r, v);
            }
        }
    }
    __syncthreads();

    // ---- coord layer: c1 = silu(y2 @ cw1 + cb1); c = (c1 . cw2 + cb2)/(sqrt(n2+eps)+1) ----
    #pragma unroll
    for (int nt = 0; nt < 8; ++nt) acc[nt] = (f32x4){0.f, 0.f, 0.f, 0.f};
    #pragma unroll
    for (int kb = 0; kb < 4; ++kb) {
        frag8 a = *(const frag8*)&sA[(mbase + lrow) * LDA + kb * 32 + quad * 8];
        #pragma unroll
        for (int nt = 0; nt < 8; ++nt) {
            frag8 b = *(const frag8*)&cw1b[(nt * 16 + lrow) * 128 + kb * 32 + quad * 8];
            acc[nt] = __builtin_amdgcn_mfma_f32_16x16x32_bf16(a, b, acc[nt], 0, 0, 0);
        }
    }
    {
        float part[4] = {0.f, 0.f, 0.f, 0.f};
        #pragma unroll
        for (int nt = 0; nt < 8; ++nt) {
            int col = nt * 16 + lrow;
            float bias = cb1[col];
            float w = cw2[col];
            #pragma unroll
            for (int r = 0; r < 4; ++r)
                part[r] += silu_f(acc[nt][r] + bias) * w;
        }
        #pragma unroll
        for (int off = 1; off < 16; off <<= 1) {
            #pragma unroll
            for (int r = 0; r < 4; ++r)
                part[r] += __shfl_xor(part[r], off);
        }
        if (lrow == 0) {
            int le = wave * 4 + quad;
            int e = e0 + le;
            if (e < E) {
                int node = sNode[le];
                float cb2f = cb2[0];
                #pragma unroll
                for (int r = 0; r < 4; ++r) {
                    float n2 = sNorm[le * 4 + r];
                    float c = (part[r] + cb2f) / (sqrtf(n2 + EPSF) + 1.f);
                    atomicAdd(&agg[(size_t)node * 12 + 0 + r], c * sXij[le * 12 + 0 + r]);
                    atomicAdd(&agg[(size_t)node * 12 + 4 + r], c * sXij[le * 12 + 4 + r]);
                    atomicAdd(&agg[(size_t)node * 12 + 8 + r], c * sXij[le * 12 + 8 + r]);
                }
                atomicAdd(&cnt[node], 1.f);
            }
        }
    }
}

// ---------------- node kernel: 16 nodes (64 rows), 256 threads, K=192 -> 128 -> 64 ----------------
__global__ __launch_bounds__(256, 3)
void node_kernel(const float* __restrict__ h, const float* __restrict__ m_i,
                 const unsigned short* __restrict__ nw1b,
                 const unsigned short* __restrict__ nw2b,
                 const float* __restrict__ nb1, const float* __restrict__ nb2,
                 float* __restrict__ out_h, int N)
{
    __shared__ unsigned short sA[64 * LDAN];
    __shared__ unsigned short sB[64 * LDB];

    const int tid = threadIdx.x;
    const int n0  = blockIdx.x * TN;

    if (tid < 128) {                                    // h -> k 0..63
        int ln = tid >> 3, d0 = (tid & 7) * 8;
        int node = n0 + ln;
        if (node < N) {
            const float4* hp = (const float4*)(h + (size_t)node * 256);
            float4 hv[8];
            #pragma unroll
            for (int q = 0; q < 8; ++q) hv[q] = hp[d0 + q];
            #pragma unroll
            for (int t = 0; t < 4; ++t) {
                float vv[8];
                #pragma unroll
                for (int q = 0; q < 8; ++q) vv[q] = ((const float*)&hv[q])[t];
                *(uint4*)&sA[(ln * 4 + t) * LDAN + d0] = pk8(vv);
            }
        }
    }
    for (int c = tid; c < 512; c += 256) {              // m_i -> k 64..191
        int ln = c >> 5, hd0 = (c & 31) * 4;
        int node = n0 + ln;
        if (node < N) {
            const float4* mp = (const float4*)(m_i + (size_t)node * 512);
            float4 mv[4];
            #pragma unroll
            for (int q = 0; q < 4; ++q) mv[q] = mp[hd0 + q];
            #pragma unroll
            for (int t = 0; t < 4; ++t) {
                uint2 u;
                u.x = pk2(((const float*)&mv[0])[t], ((const float*)&mv[1])[t]);
                u.y = pk2(((const float*)&mv[2])[t], ((const float*)&mv[3])[t]);
                *(uint2*)&sA[(ln * 4 + t) * LDAN + 64 + hd0] = u;
            }
        }
    }
    __syncthreads();

    const int lane = tid & 63;
    const int wave = tid >> 6;
    const int lrow = lane & 15;
    const int quad = lane >> 4;
    const int mbase = wave * 16;

    f32x4 acc[8];
    #pragma unroll
    for (int nt = 0; nt < 8; ++nt) acc[nt] = (f32x4){0.f, 0.f, 0.f, 0.f};
    #pragma unroll
    for (int kb = 0; kb < 6; ++kb) {
        frag8 a = *(const frag8*)&sA[(mbase + lrow) * LDAN + kb * 32 + quad * 8];
        #pragma unroll
        for (int nt = 0; nt < 8; ++nt) {
            frag8 b = *(const frag8*)&nw1b[(nt * 16 + lrow) * 192 + kb * 32 + quad * 8];
            acc[nt] = __builtin_amdgcn_mfma_f32_16x16x32_bf16(a, b, acc[nt], 0, 0, 0);
        }
    }
    #pragma unroll
    for (int nt = 0; nt < 8; ++nt) {
        int col = nt * 16 + lrow;
        float bias = nb1[col];
        #pragma unroll
        for (int r = 0; r < 4; ++r)
            sB[(mbase + quad * 4 + r) * LDB + col] = f2b(silu_f(acc[nt][r] + bias));
    }
    __syncthreads();

    f32x4 acc2[4];
    #pragma unroll
    for (int nt = 0; nt < 4; ++nt) acc2[nt] = (f32x4){0.f, 0.f, 0.f, 0.f};
    #pragma unroll
    for (int kb = 0; kb < 4; ++kb) {
        frag8 a = *(const frag8*)&sB[(mbase + lrow) * LDB + kb * 32 + quad * 8];
        #pragma unroll
        for (int nt = 0; nt < 4; ++nt) {
            frag8 b = *(const frag8*)&nw2b[(nt * 16 + lrow) * 128 + kb * 32 + quad * 8];
            acc2[nt] = __builtin_amdgcn_mfma_f32_16x16x32_bf16(a, b, acc2[nt], 0, 0, 0);
        }
    }
    {
        int ln = wave * 4 + quad;
        int node = n0 + ln;
        if (node < N) {
            float* op = out_h + (size_t)node * 256;
            #pragma unroll
            for (int nt = 0; nt < 4; ++nt) {
                int col = nt * 16 + lrow;
                float bias = nb2[col];
                float4 ov = { acc2[nt][0] + bias, acc2[nt][1] + bias,
                              acc2[nt][2] + bias, acc2[nt][3] + bias };
                *(float4*)&op[col * 4] = ov;
            }
        }
    }
}

// ---------------- coord update ----------------
__global__ void coord_update(const float* __restrict__ x, const float* __restrict__ agg,
                             const float* __restrict__ cnt, float* __restrict__ out_x, int N)
{
    int i = blockIdx.x * 256 + threadIdx.x;
    if (i < N * 12) {
        int n = i / 12;
        out_x[i] = x[i] + agg[i] / fmaxf(cnt[n], 1.f);
    }
}

extern "C" void kernel_launch(void* const* d_in, const int* in_sizes, int n_in,
                              void* d_out, int out_size, void* d_ws, size_t ws_size,
                              hipStream_t stream)
{
    const float* x   = (const float*)d_in[0];
    const float* h   = (const float*)d_in[1];
    const int*   ei  = (const int*)d_in[2];
    const float* ea  = (const float*)d_in[3];
    const float* w1  = (const float*)d_in[5];
    const float* b1  = (const float*)d_in[6];
    const float* w2  = (const float*)d_in[7];
    const float* b2  = (const float*)d_in[8];
    const float* cw1 = (const float*)d_in[9];
    const float* cb1 = (const float*)d_in[10];
    const float* cw2 = (const float*)d_in[11];
    const float* cb2 = (const float*)d_in[12];
    const float* nw1 = (const float*)d_in[13];
    const float* nb1 = (const float*)d_in[14];
    const float* nw2 = (const float*)d_in[15];
    const float* nb2 = (const float*)d_in[16];

    const int N = in_sizes[0] / 12;
    const int E = in_sizes[2] / 2;

    unsigned short* wb = (unsigned short*)d_ws;
    const unsigned short* w1b  = wb;
    const unsigned short* w2b  = wb + 20480;
    const unsigned short* cw1b = wb + 36864;
    const unsigned short* nw1b = wb + 53248;
    const unsigned short* nw2b = wb + 77824;

    float* m_i = (float*)((char*)d_ws + 172032);
    float* agg = m_i + (size_t)N * 512;
    float* cnt = agg + (size_t)N * 12;

    hipMemsetAsync(m_i, 0, (size_t)N * 525 * sizeof(float), stream);
    prep_weights<<<336, 256, 0, stream>>>(w1, w2, cw1, nw1, nw2, wb);

    float* out_x = (float*)d_out;
    float* out_h = out_x + (size_t)N * 12;

    edge_kernel<<<(E + TE - 1) / TE, 256, 0, stream>>>(
        x, h, ei, ea, w1b, w2b, cw1b, b1, b2, cb1, cb2, cw2, m_i, agg, cnt, N, E);
    node_kernel<<<(N + TN - 1) / TN, 256, 0, stream>>>(
        h, m_i, nw1b, nw2b, nb1, nb2, out_h, N);
    coord_update<<<(N * 12 + 255) / 256, 256, 0, stream>>>(x, agg, cnt, out_x, N);
}

// Round 5
// 1412.823 us; speedup vs baseline: 1.8806x; 1.8806x over previous
//
#include <hip/hip_runtime.h>
#include <math.h>

#define T 4
#define HH 64
#define HE 16
#define HD 128
#define EPSF 1e-8f

#define TE 16                     // edges per block (edge kernel)
#define ROWS 64                   // TE*T merged rows
#define LDA 168     // k-stride bf16 elems for K=160 buf: 336B = 84 banks == 20 mod 32
#define LDB 136     // K=128 activation buf: 272B = 68 banks == 4 mod 32
#define TN 16       // nodes per block (node kernel)
#define LDAN 200    // K=192 buf: 400B == 4 mod 32

using frag8 = __attribute__((ext_vector_type(8))) short;
using f32x4 = __attribute__((ext_vector_type(4))) float;

__device__ __forceinline__ float silu_f(float v) { return v / (1.f + __expf(-v)); }

__device__ __forceinline__ unsigned short f2b(float f) {
    union { float f; unsigned u; } v; v.f = f;
    unsigned r = v.u + 0x7FFF + ((v.u >> 16) & 1);   // RNE
    return (unsigned short)(r >> 16);
}
__device__ __forceinline__ unsigned pk2(float a, float b) {
    return (unsigned)f2b(a) | ((unsigned)f2b(b) << 16);
}
__device__ __forceinline__ uint4 pk8(const float* v) {
    uint4 r;
    r.x = pk2(v[0], v[1]); r.y = pk2(v[2], v[3]);
    r.z = pk2(v[4], v[5]); r.w = pk2(v[6], v[7]);
    return r;
}
__device__ __forceinline__ float b2f(unsigned u16) {
    union { unsigned u; float f; } v; v.u = u16 << 16; return v.f;
}

// ---------------- weight prep: fp32 -> bf16, transposed to [n][k] ----------------
__global__ void prep_weights(const float* __restrict__ w1, const float* __restrict__ w2,
                             const float* __restrict__ cw1, const float* __restrict__ nw1,
                             const float* __restrict__ nw2, unsigned short* __restrict__ wb)
{
    int i = blockIdx.x * 256 + threadIdx.x;
    if (i < 20480) {
        int n = i / 160, k = i - n * 160;
        float v;
        if (k < 128)      v = w1[k * 128 + n];
        else if (k < 144) v = w1[(129 + (k - 128)) * 128 + n];   // ea dims
        else if (k == 144) v = w1[128 * 128 + n];                 // n2 dim
        else              v = 0.f;
        wb[i] = f2b(v);
    } else if (i < 36864) {
        int j = i - 20480; int n = j >> 7, k = j & 127;
        wb[i] = f2b(w2[k * 128 + n]);
    } else if (i < 53248) {
        int j = i - 36864; int n = j >> 7, k = j & 127;
        wb[i] = f2b(cw1[k * 128 + n]);
    } else if (i < 77824) {
        int j = i - 53248; int n = j / 192, k = j - n * 192;
        wb[i] = f2b(nw1[k * 128 + n]);
    } else if (i < 86016) {
        int j = i - 77824; int n = j >> 7, k = j & 127;
        wb[i] = f2b(nw2[k * 64 + n]);
    }
}

// ---------------- CSR build: edges sorted by destination (row) node ----------------
__global__ void hist_kernel(const int* __restrict__ ei, int* __restrict__ deg, int E) {
    int e = blockIdx.x * 256 + threadIdx.x;
    if (e < E) atomicAdd(&deg[ei[e]], 1);
}

__global__ __launch_bounds__(1024)
void scan_kernel(const int* __restrict__ deg, int* __restrict__ start, int N) {
    __shared__ int part[1024];
    int tid = threadIdx.x;
    int chunk = (N + 1023) >> 10;
    int b0 = tid * chunk;
    int s = 0;
    for (int i = 0; i < chunk; ++i) { int idx = b0 + i; if (idx < N) s += deg[idx]; }
    part[tid] = s;
    __syncthreads();
    for (int off = 1; off < 1024; off <<= 1) {
        int v = (tid >= off) ? part[tid - off] : 0;
        __syncthreads();
        part[tid] += v;
        __syncthreads();
    }
    int prefix = (tid > 0) ? part[tid - 1] : 0;
    for (int i = 0; i < chunk; ++i) {
        int idx = b0 + i;
        if (idx < N) { start[idx] = prefix; prefix += deg[idx]; }
    }
    if (tid == 1023) start[N] = part[1023];
}

__global__ void scatter_kernel(const int* __restrict__ ei, const int* __restrict__ start,
                               int* __restrict__ cursor, int* __restrict__ list, int E) {
    int e = blockIdx.x * 256 + threadIdx.x;
    if (e < E) {
        int r = ei[e];
        int p = atomicAdd(&cursor[r], 1);
        list[start[r] + p] = e;
    }
}

// ---------------- edge kernel: 16 CSR-ordered edges (64 rows), 256 threads ----------------
// m_i accumulated via per-block segmented reduction (few atomics per run), agg atomics direct.
__global__ __launch_bounds__(256, 4)
void edge_kernel(const float* __restrict__ x, const float* __restrict__ h,
                 const int* __restrict__ ei, const float* __restrict__ ea,
                 const int* __restrict__ list,
                 const unsigned short* __restrict__ w1b,
                 const unsigned short* __restrict__ w2b,
                 const unsigned short* __restrict__ cw1b,
                 const float* __restrict__ b1, const float* __restrict__ b2,
                 const float* __restrict__ cb1, const float* __restrict__ cb2,
                 const float* __restrict__ cw2,
                 float* __restrict__ m_i,
                 float* __restrict__ agg,
                 int N, int E)
{
    __shared__ unsigned short sA[ROWS * LDA];   // m_in (K=160), later y2 (K=128)
    __shared__ unsigned short sB[ROWS * LDB];   // y1 / c1
    __shared__ float sXij[TE * 12];
    __shared__ float sNorm[ROWS];
    __shared__ int   sNode[TE];

    const int tid = threadIdx.x;
    const int e0  = blockIdx.x * TE;

    if (tid < TE) {
        int p = e0 + tid;
        sNode[tid] = (p < E) ? ei[list[p]] : -1;
    }
    if (tid >= TE && tid < TE + TE * 12) {
        int j = tid - TE;
        int le = j / 12, i = j - le * 12;     // i = axis*4 + t
        int p = e0 + le;
        float d = 0.f;
        if (p < E) {
            int eid = list[p];
            int rn = ei[eid], cn = ei[E + eid];
            d = x[rn * 12 + i] - x[cn * 12 + i];
        }
        sXij[j] = d;
    }
    // h gather: 16 le x 2 half x 8 d0 = 256 assignments, 128B contiguous each
    {
        int half = tid >> 7;
        int t7 = tid & 127;
        int le = t7 >> 3, d0 = (t7 & 7) * 8;
        int p = e0 + le;
        if (p < E) {
            int eid = list[p];
            int node = ei[half ? (E + eid) : eid];
            const float4* hp = (const float4*)(h + (size_t)node * 256);
            float4 hv[8];
            #pragma unroll
            for (int q = 0; q < 8; ++q) hv[q] = hp[d0 + q];
            #pragma unroll
            for (int t = 0; t < 4; ++t) {
                float vv[8];
                #pragma unroll
                for (int q = 0; q < 8; ++q) vv[q] = ((const float*)&hv[q])[t];
                *(uint4*)&sA[(le * 4 + t) * LDA + half * 64 + d0] = pk8(vv);
            }
        }
    }
    // edge_attr: k 128..143
    if (tid < 64) {
        int le = tid >> 2, eh0 = (tid & 3) * 4;
        int p = e0 + le;
        if (p < E) {
            int eid = list[p];
            const float4* ap = (const float4*)(ea + (size_t)eid * 64);
            float4 av[4];
            #pragma unroll
            for (int q = 0; q < 4; ++q) av[q] = ap[eh0 + q];
            #pragma unroll
            for (int t = 0; t < 4; ++t) {
                uint2 u;
                u.x = pk2(((const float*)&av[0])[t], ((const float*)&av[1])[t]);
                u.y = pk2(((const float*)&av[2])[t], ((const float*)&av[3])[t]);
                *(uint2*)&sA[(le * 4 + t) * LDA + 128 + eh0] = u;
            }
        }
    }
    __syncthreads();
    if (tid < ROWS) {
        int le = tid >> 2, t = tid & 3;
        float a0 = sXij[le * 12 + t], a1 = sXij[le * 12 + 4 + t], a2 = sXij[le * 12 + 8 + t];
        float n2 = a0 * a0 + a1 * a1 + a2 * a2;
        sNorm[tid] = n2;
        uint4 z = {0, 0, 0, 0};
        *(uint4*)&sA[tid * LDA + 144] = z;
        *(uint4*)&sA[tid * LDA + 152] = z;
        sA[tid * LDA + 144] = f2b(n2);
    }
    __syncthreads();

    const int lane = tid & 63;
    const int wave = tid >> 6;
    const int lrow = lane & 15;
    const int quad = lane >> 4;
    const int mbase = wave * 16;

    // ---- layer 1 ----
    f32x4 acc[8];
    #pragma unroll
    for (int nt = 0; nt < 8; ++nt) acc[nt] = (f32x4){0.f, 0.f, 0.f, 0.f};
    #pragma unroll
    for (int kb = 0; kb < 5; ++kb) {
        frag8 a = *(const frag8*)&sA[(mbase + lrow) * LDA + kb * 32 + quad * 8];
        #pragma unroll
        for (int nt = 0; nt < 8; ++nt) {
            frag8 b = *(const frag8*)&w1b[(nt * 16 + lrow) * 160 + kb * 32 + quad * 8];
            acc[nt] = __builtin_amdgcn_mfma_f32_16x16x32_bf16(a, b, acc[nt], 0, 0, 0);
        }
    }
    #pragma unroll
    for (int nt = 0; nt < 8; ++nt) {
        int col = nt * 16 + lrow;
        float bias = b1[col];
        #pragma unroll
        for (int r = 0; r < 4; ++r)
            sB[(mbase + quad * 4 + r) * LDB + col] = f2b(silu_f(acc[nt][r] + bias));
    }
    __syncthreads();

    // ---- layer 2: y2 = silu(y1 @ w2 + b2) -> sA (bf16) ----
    #pragma unroll
    for (int nt = 0; nt < 8; ++nt) acc[nt] = (f32x4){0.f, 0.f, 0.f, 0.f};
    #pragma unroll
    for (int kb = 0; kb < 4; ++kb) {
        frag8 a = *(const frag8*)&sB[(mbase + lrow) * LDB + kb * 32 + quad * 8];
        #pragma unroll
        for (int nt = 0; nt < 8; ++nt) {
            frag8 b = *(const frag8*)&w2b[(nt * 16 + lrow) * 128 + kb * 32 + quad * 8];
            acc[nt] = __builtin_amdgcn_mfma_f32_16x16x32_bf16(a, b, acc[nt], 0, 0, 0);
        }
    }
    #pragma unroll
    for (int nt = 0; nt < 8; ++nt) {
        int col = nt * 16 + lrow;
        float bias = b2[col];
        #pragma unroll
        for (int r = 0; r < 4; ++r)
            sA[(mbase + quad * 4 + r) * LDA + col] = f2b(silu_f(acc[nt][r] + bias));
    }
    __syncthreads();

    // ---- coord layer: c1 = silu(y2 @ cw1 + cb1) ----
    #pragma unroll
    for (int nt = 0; nt < 8; ++nt) acc[nt] = (f32x4){0.f, 0.f, 0.f, 0.f};
    #pragma unroll
    for (int kb = 0; kb < 4; ++kb) {
        frag8 a = *(const frag8*)&sA[(mbase + lrow) * LDA + kb * 32 + quad * 8];
        #pragma unroll
        for (int nt = 0; nt < 8; ++nt) {
            frag8 b = *(const frag8*)&cw1b[(nt * 16 + lrow) * 128 + kb * 32 + quad * 8];
            acc[nt] = __builtin_amdgcn_mfma_f32_16x16x32_bf16(a, b, acc[nt], 0, 0, 0);
        }
    }

    // ---- m_i: segmented reduction over CSR-contiguous same-node runs ----
    // edges in this block are sorted by destination; sNode[] is monotone.
    // each thread owns 2 of the 512 (t,col) elements; branches are wave-uniform.
    {
        #pragma unroll
        for (int z = 0; z < 2; ++z) {
            int elem = tid + z * 256;            // elem = t*128 + col
            int t = elem >> 7, col = elem & 127;
            float run = 0.f;
            int cur = sNode[0];
            #pragma unroll 1
            for (int le = 0; le < TE; ++le) {
                int nd = sNode[le];
                if (nd != cur) {
                    if (cur >= 0) atomicAdd(&m_i[(size_t)cur * 512 + col * 4 + t], run);
                    run = 0.f; cur = nd;
                }
                if (nd >= 0) run += b2f((unsigned)sA[(le * 4 + t) * LDA + col]);
            }
            if (cur >= 0) atomicAdd(&m_i[(size_t)cur * 512 + col * 4 + t], run);
        }
    }

    // ---- coord epilogue: c = (c1 . cw2 + cb2)/(sqrt(n2+eps)+1); agg atomics ----
    {
        float part[4] = {0.f, 0.f, 0.f, 0.f};
        #pragma unroll
        for (int nt = 0; nt < 8; ++nt) {
            int col = nt * 16 + lrow;
            float bias = cb1[col];
            float w = cw2[col];
            #pragma unroll
            for (int r = 0; r < 4; ++r)
                part[r] += silu_f(acc[nt][r] + bias) * w;
        }
        #pragma unroll
        for (int off = 1; off < 16; off <<= 1) {
            #pragma unroll
            for (int r = 0; r < 4; ++r)
                part[r] += __shfl_xor(part[r], off);
        }
        if (lrow == 0) {
            int le = wave * 4 + quad;
            int p = e0 + le;
            if (p < E) {
                int node = sNode[le];
                float cb2f = cb2[0];
                #pragma unroll
                for (int r = 0; r < 4; ++r) {
                    float n2 = sNorm[le * 4 + r];
                    float c = (part[r] + cb2f) / (sqrtf(n2 + EPSF) + 1.f);
                    atomicAdd(&agg[(size_t)node * 12 + 0 + r], c * sXij[le * 12 + 0 + r]);
                    atomicAdd(&agg[(size_t)node * 12 + 4 + r], c * sXij[le * 12 + 4 + r]);
                    atomicAdd(&agg[(size_t)node * 12 + 8 + r], c * sXij[le * 12 + 8 + r]);
                }
            }
        }
    }
}

// ---------------- node kernel: 16 nodes (64 rows), 256 threads, K=192 -> 128 -> 64 ----------------
__global__ __launch_bounds__(256, 3)
void node_kernel(const float* __restrict__ h, const float* __restrict__ m_i,
                 const unsigned short* __restrict__ nw1b,
                 const unsigned short* __restrict__ nw2b,
                 const float* __restrict__ nb1, const float* __restrict__ nb2,
                 float* __restrict__ out_h, int N)
{
    __shared__ unsigned short sA[64 * LDAN];
    __shared__ unsigned short sB[64 * LDB];

    const int tid = threadIdx.x;
    const int n0  = blockIdx.x * TN;

    if (tid < 128) {                                    // h -> k 0..63
        int ln = tid >> 3, d0 = (tid & 7) * 8;
        int node = n0 + ln;
        if (node < N) {
            const float4* hp = (const float4*)(h + (size_t)node * 256);
            float4 hv[8];
            #pragma unroll
            for (int q = 0; q < 8; ++q) hv[q] = hp[d0 + q];
            #pragma unroll
            for (int t = 0; t < 4; ++t) {
                float vv[8];
                #pragma unroll
                for (int q = 0; q < 8; ++q) vv[q] = ((const float*)&hv[q])[t];
                *(uint4*)&sA[(ln * 4 + t) * LDAN + d0] = pk8(vv);
            }
        }
    }
    for (int c = tid; c < 512; c += 256) {              // m_i -> k 64..191
        int ln = c >> 5, hd0 = (c & 31) * 4;
        int node = n0 + ln;
        if (node < N) {
            const float4* mp = (const float4*)(m_i + (size_t)node * 512);
            float4 mv[4];
            #pragma unroll
            for (int q = 0; q < 4; ++q) mv[q] = mp[hd0 + q];
            #pragma unroll
            for (int t = 0; t < 4; ++t) {
                uint2 u;
                u.x = pk2(((const float*)&mv[0])[t], ((const float*)&mv[1])[t]);
                u.y = pk2(((const float*)&mv[2])[t], ((const float*)&mv[3])[t]);
                *(uint2*)&sA[(ln * 4 + t) * LDAN + 64 + hd0] = u;
            }
        }
    }
    __syncthreads();

    const int lane = tid & 63;
    const int wave = tid >> 6;
    const int lrow = lane & 15;
    const int quad = lane >> 4;
    const int mbase = wave * 16;

    f32x4 acc[8];
    #pragma unroll
    for (int nt = 0; nt < 8; ++nt) acc[nt] = (f32x4){0.f, 0.f, 0.f, 0.f};
    #pragma unroll
    for (int kb = 0; kb < 6; ++kb) {
        frag8 a = *(const frag8*)&sA[(mbase + lrow) * LDAN + kb * 32 + quad * 8];
        #pragma unroll
        for (int nt = 0; nt < 8; ++nt) {
            frag8 b = *(const frag8*)&nw1b[(nt * 16 + lrow) * 192 + kb * 32 + quad * 8];
            acc[nt] = __builtin_amdgcn_mfma_f32_16x16x32_bf16(a, b, acc[nt], 0, 0, 0);
        }
    }
    #pragma unroll
    for (int nt = 0; nt < 8; ++nt) {
        int col = nt * 16 + lrow;
        float bias = nb1[col];
        #pragma unroll
        for (int r = 0; r < 4; ++r)
            sB[(mbase + quad * 4 + r) * LDB + col] = f2b(silu_f(acc[nt][r] + bias));
    }
    __syncthreads();

    f32x4 acc2[4];
    #pragma unroll
    for (int nt = 0; nt < 4; ++nt) acc2[nt] = (f32x4){0.f, 0.f, 0.f, 0.f};
    #pragma unroll
    for (int kb = 0; kb < 4; ++kb) {
        frag8 a = *(const frag8*)&sB[(mbase + lrow) * LDB + kb * 32 + quad * 8];
        #pragma unroll
        for (int nt = 0; nt < 4; ++nt) {
            frag8 b = *(const frag8*)&nw2b[(nt * 16 + lrow) * 128 + kb * 32 + quad * 8];
            acc2[nt] = __builtin_amdgcn_mfma_f32_16x16x32_bf16(a, b, acc2[nt], 0, 0, 0);
        }
    }
    {
        int ln = wave * 4 + quad;
        int node = n0 + ln;
        if (node < N) {
            float* op = out_h + (size_t)node * 256;
            #pragma unroll
            for (int nt = 0; nt < 4; ++nt) {
                int col = nt * 16 + lrow;
                float bias = nb2[col];
                float4 ov = { acc2[nt][0] + bias, acc2[nt][1] + bias,
                              acc2[nt][2] + bias, acc2[nt][3] + bias };
                *(float4*)&op[col * 4] = ov;
            }
        }
    }
}

// ---------------- coord update ----------------
__global__ void coord_update(const float* __restrict__ x, const float* __restrict__ agg,
                             const int* __restrict__ deg, float* __restrict__ out_x, int N)
{
    int i = blockIdx.x * 256 + threadIdx.x;
    if (i < N * 12) {
        int n = i / 12;
        out_x[i] = x[i] + agg[i] / fmaxf((float)deg[n], 1.f);
    }
}

extern "C" void kernel_launch(void* const* d_in, const int* in_sizes, int n_in,
                              void* d_out, int out_size, void* d_ws, size_t ws_size,
                              hipStream_t stream)
{
    const float* x   = (const float*)d_in[0];
    const float* h   = (const float*)d_in[1];
    const int*   ei  = (const int*)d_in[2];
    const float* ea  = (const float*)d_in[3];
    const float* w1  = (const float*)d_in[5];
    const float* b1  = (const float*)d_in[6];
    const float* w2  = (const float*)d_in[7];
    const float* b2  = (const float*)d_in[8];
    const float* cw1 = (const float*)d_in[9];
    const float* cb1 = (const float*)d_in[10];
    const float* cw2 = (const float*)d_in[11];
    const float* cb2 = (const float*)d_in[12];
    const float* nw1 = (const float*)d_in[13];
    const float* nb1 = (const float*)d_in[14];
    const float* nw2 = (const float*)d_in[15];
    const float* nb2 = (const float*)d_in[16];

    const int N = in_sizes[0] / 12;
    const int E = in_sizes[2] / 2;

    // ---- workspace layout (bytes); total ~44.5 MB ----
    char* ws = (char*)d_ws;
    unsigned short* wb = (unsigned short*)ws;              // 172032 B
    size_t o = 172032;
    int*   deg    = (int*)(ws + o);    o += (size_t)N * 4;
    int*   cursor = (int*)(ws + o);    o += (size_t)N * 4;
    float* agg    = (float*)(ws + o);  o += (size_t)N * 48;
    size_t zero_end = o;
    int*   start  = (int*)(ws + o);    o += (size_t)(N + 1) * 4;
    o = (o + 1023) & ~(size_t)1023;
    int*   list   = (int*)(ws + o);    o += (size_t)E * 4;
    o = (o + 1023) & ~(size_t)1023;
    float* m_i    = (float*)(ws + o);                      // N*512 fp32 = 41 MB

    const unsigned short* w1b  = wb;
    const unsigned short* w2b  = wb + 20480;
    const unsigned short* cw1b = wb + 36864;
    const unsigned short* nw1b = wb + 53248;
    const unsigned short* nw2b = wb + 77824;

    hipMemsetAsync(deg, 0, zero_end - 172032, stream);      // deg + cursor + agg
    hipMemsetAsync(m_i, 0, (size_t)N * 512 * sizeof(float), stream);
    prep_weights<<<336, 256, 0, stream>>>(w1, w2, cw1, nw1, nw2, wb);
    hist_kernel<<<(E + 255) / 256, 256, 0, stream>>>(ei, deg, E);
    scan_kernel<<<1, 1024, 0, stream>>>(deg, start, N);
    scatter_kernel<<<(E + 255) / 256, 256, 0, stream>>>(ei, start, cursor, list, E);

    float* out_x = (float*)d_out;
    float* out_h = out_x + (size_t)N * 12;

    edge_kernel<<<(E + TE - 1) / TE, 256, 0, stream>>>(
        x, h, ei, ea, list, w1b, w2b, cw1b, b1, b2, cb1, cb2, cw2, m_i, agg, N, E);
    node_kernel<<<(N + TN - 1) / TN, 256, 0, stream>>>(
        h, m_i, nw1b, nw2b, nb1, nb2, out_h, N);
    coord_update<<<(N * 12 + 255) / 256, 256, 0, stream>>>(x, agg, deg, out_x, N);
}

// Round 6
// 1346.849 us; speedup vs baseline: 1.9728x; 1.0490x over previous
//
#include <hip/hip_runtime.h>
#include <math.h>

#define T 4
#define HH 64
#define HE 16
#define HD 128
#define EPSF 1e-8f

#define TE 16                     // edges per block (edge kernel)
#define ROWS 64                   // TE*T merged rows
#define LDA 168     // k-stride bf16 elems for K=160 buf: 336B = 84 banks == 20 mod 32
#define LDB 136     // K=128 buf: 272B = 68 banks == 4 mod 32
#define TN 16       // nodes per block (node kernel)
#define LDAN 200    // K=192 buf: 400B == 4 mod 32

using frag8 = __attribute__((ext_vector_type(8))) short;
using f32x4 = __attribute__((ext_vector_type(4))) float;

__device__ __forceinline__ float silu_f(float v) { return v / (1.f + __expf(-v)); }

__device__ __forceinline__ unsigned short f2b(float f) {
    union { float f; unsigned u; } v; v.f = f;
    unsigned r = v.u + 0x7FFF + ((v.u >> 16) & 1);   // RNE
    return (unsigned short)(r >> 16);
}
__device__ __forceinline__ unsigned pk2(float a, float b) {
    return (unsigned)f2b(a) | ((unsigned)f2b(b) << 16);
}
__device__ __forceinline__ uint4 pk8(const float* v) {
    uint4 r;
    r.x = pk2(v[0], v[1]); r.y = pk2(v[2], v[3]);
    r.z = pk2(v[4], v[5]); r.w = pk2(v[6], v[7]);
    return r;
}
__device__ __forceinline__ float b2f(unsigned u16) {
    union { unsigned u; float f; } v; v.u = u16 << 16; return v.f;
}
__device__ __forceinline__ void lds_fence() {
    asm volatile("s_waitcnt lgkmcnt(0)" ::: "memory");
}

// ---------------- weight prep: fp32 -> bf16, transposed to [n][k] ----------------
__global__ void prep_weights(const float* __restrict__ w1, const float* __restrict__ w2,
                             const float* __restrict__ cw1, const float* __restrict__ nw1,
                             const float* __restrict__ nw2, unsigned short* __restrict__ wb)
{
    int i = blockIdx.x * 256 + threadIdx.x;
    if (i < 20480) {
        int n = i / 160, k = i - n * 160;
        float v;
        if (k < 128)      v = w1[k * 128 + n];
        else if (k < 144) v = w1[(129 + (k - 128)) * 128 + n];   // ea dims
        else if (k == 144) v = w1[128 * 128 + n];                 // n2 dim
        else              v = 0.f;
        wb[i] = f2b(v);
    } else if (i < 36864) {
        int j = i - 20480; int n = j >> 7, k = j & 127;
        wb[i] = f2b(w2[k * 128 + n]);
    } else if (i < 53248) {
        int j = i - 36864; int n = j >> 7, k = j & 127;
        wb[i] = f2b(cw1[k * 128 + n]);
    } else if (i < 77824) {
        int j = i - 53248; int n = j / 192, k = j - n * 192;
        wb[i] = f2b(nw1[k * 128 + n]);
    } else if (i < 86016) {
        int j = i - 77824; int n = j >> 7, k = j & 127;
        wb[i] = f2b(nw2[k * 64 + n]);
    }
}

// ---------------- CSR build: edges sorted by destination (row) node ----------------
__global__ void hist_kernel(const int* __restrict__ ei, int* __restrict__ deg, int E) {
    int e = blockIdx.x * 256 + threadIdx.x;
    if (e < E) atomicAdd(&deg[ei[e]], 1);
}

__global__ __launch_bounds__(1024)
void scan_kernel(const int* __restrict__ deg, int* __restrict__ start, int N) {
    __shared__ int part[1024];
    int tid = threadIdx.x;
    int chunk = (N + 1023) >> 10;
    int b0 = tid * chunk;
    int s = 0;
    for (int i = 0; i < chunk; ++i) { int idx = b0 + i; if (idx < N) s += deg[idx]; }
    part[tid] = s;
    __syncthreads();
    for (int off = 1; off < 1024; off <<= 1) {
        int v = (tid >= off) ? part[tid - off] : 0;
        __syncthreads();
        part[tid] += v;
        __syncthreads();
    }
    int prefix = (tid > 0) ? part[tid - 1] : 0;
    for (int i = 0; i < chunk; ++i) {
        int idx = b0 + i;
        if (idx < N) { start[idx] = prefix; prefix += deg[idx]; }
    }
    if (tid == 1023) start[N] = part[1023];
}

__global__ void scatter_kernel(const int* __restrict__ ei, const int* __restrict__ start,
                               int* __restrict__ cursor, int* __restrict__ list, int E) {
    int e = blockIdx.x * 256 + threadIdx.x;
    if (e < E) {
        int r = ei[e];
        int p = atomicAdd(&cursor[r], 1);
        list[start[r] + p] = e;
    }
}

// ---------------- edge kernel: 16 CSR-ordered edges, 256 threads ----------------
// Each wave owns 4 edges end-to-end with wave-private LDS; ONE barrier total
// (before the block-wide m_i segmented reduction).
__global__ __launch_bounds__(256, 4)
void edge_kernel(const float* __restrict__ x, const float* __restrict__ h,
                 const int* __restrict__ ei, const float* __restrict__ ea,
                 const int* __restrict__ list,
                 const unsigned short* __restrict__ w1b,
                 const unsigned short* __restrict__ w2b,
                 const unsigned short* __restrict__ cw1b,
                 const float* __restrict__ b1, const float* __restrict__ b2,
                 const float* __restrict__ cb1, const float* __restrict__ cb2,
                 const float* __restrict__ cw2,
                 float* __restrict__ m_i,
                 float* __restrict__ agg,
                 int N, int E)
{
    __shared__ unsigned short sA[ROWS * LDA];   // staging (K=160) then y1 (K=128), wave-private slices
    __shared__ unsigned short sY[ROWS * LDB];   // y2, block-wide (read by m_i reduction)
    __shared__ float sXij[TE * 12];
    __shared__ float sNorm[ROWS];
    __shared__ int   sNode[TE];

    const int tid  = threadIdx.x;
    const int e0   = blockIdx.x * TE;
    const int lane = tid & 63;
    const int wave = tid >> 6;
    const int eb   = wave * 4;                  // wave's first local edge

    // ======== phase A: wave-local, no barriers ========
    // sNode (lanes 0..3)
    if (lane < 4) {
        int p = e0 + eb + lane;
        sNode[eb + lane] = (p < E) ? ei[list[p]] : -1;
    }
    // x_ij (lanes 0..47)
    if (lane < 48) {
        int le = lane / 12, i = lane - le * 12;   // i = axis*4 + t
        int p = e0 + eb + le;
        float d = 0.f;
        if (p < E) {
            int eid = list[p];
            d = x[ei[eid] * 12 + i] - x[ei[E + eid] * 12 + i];
        }
        sXij[(eb + le) * 12 + i] = d;
    }
    // h gather: 4 le x 2 half x 8 d0 = 64 tasks = 1/lane
    {
        int le = lane >> 4, half = (lane >> 3) & 1, d0 = (lane & 7) * 8;
        int p = e0 + eb + le;
        if (p < E) {
            int eid = list[p];
            int node = ei[half ? (E + eid) : eid];
            const float4* hp = (const float4*)(h + (size_t)node * 256);
            float4 hv[8];
            #pragma unroll
            for (int q = 0; q < 8; ++q) hv[q] = hp[d0 + q];
            #pragma unroll
            for (int t = 0; t < 4; ++t) {
                float vv[8];
                #pragma unroll
                for (int q = 0; q < 8; ++q) vv[q] = ((const float*)&hv[q])[t];
                *(uint4*)&sA[((eb + le) * 4 + t) * LDA + half * 64 + d0] = pk8(vv);
            }
        }
    }
    // edge_attr: 4 le x 4 chunks = 16 tasks (lanes 0..15), k 128..143
    if (lane < 16) {
        int le = lane >> 2, eh0 = (lane & 3) * 4;
        int p = e0 + eb + le;
        if (p < E) {
            const float4* ap = (const float4*)(ea + (size_t)list[p] * 64);
            float4 av[4];
            #pragma unroll
            for (int q = 0; q < 4; ++q) av[q] = ap[eh0 + q];
            #pragma unroll
            for (int t = 0; t < 4; ++t) {
                uint2 u;
                u.x = pk2(((const float*)&av[0])[t], ((const float*)&av[1])[t]);
                u.y = pk2(((const float*)&av[2])[t], ((const float*)&av[3])[t]);
                *(uint2*)&sA[((eb + le) * 4 + t) * LDA + 128 + eh0] = u;
            }
        }
    }
    lds_fence();   // xij writes (lanes 0..47) -> n2 reads (lanes 0..15), same wave
    // n2 at k=144, zero-pad 145..159 (lanes 0..15 -> wave's 16 rows)
    if (lane < 16) {
        int row = wave * 16 + lane;
        int le = eb + (lane >> 2), t = lane & 3;
        float a0 = sXij[le * 12 + t], a1 = sXij[le * 12 + 4 + t], a2 = sXij[le * 12 + 8 + t];
        float n2 = a0 * a0 + a1 * a1 + a2 * a2;
        sNorm[row] = n2;
        uint4 z = {0, 0, 0, 0};
        *(uint4*)&sA[row * LDA + 144] = z;
        *(uint4*)&sA[row * LDA + 152] = z;
        sA[row * LDA + 144] = f2b(n2);
    }
    lds_fence();

    const int lrow = lane & 15;
    const int quad = lane >> 4;
    const int mbase = wave * 16;

    // ---- layer 1: [16 x 160] @ [160 x 128] ----
    f32x4 acc[8];
    #pragma unroll
    for (int nt = 0; nt < 8; ++nt) acc[nt] = (f32x4){0.f, 0.f, 0.f, 0.f};
    #pragma unroll
    for (int kb = 0; kb < 5; ++kb) {
        frag8 a = *(const frag8*)&sA[(mbase + lrow) * LDA + kb * 32 + quad * 8];
        #pragma unroll
        for (int nt = 0; nt < 8; ++nt) {
            frag8 b = *(const frag8*)&w1b[(nt * 16 + lrow) * 160 + kb * 32 + quad * 8];
            acc[nt] = __builtin_amdgcn_mfma_f32_16x16x32_bf16(a, b, acc[nt], 0, 0, 0);
        }
    }
    // y1 overlays wave's own staging slice (fully consumed above)
    #pragma unroll
    for (int nt = 0; nt < 8; ++nt) {
        int col = nt * 16 + lrow;
        float bias = b1[col];
        #pragma unroll
        for (int r = 0; r < 4; ++r)
            sA[(mbase + quad * 4 + r) * LDA + col] = f2b(silu_f(acc[nt][r] + bias));
    }
    lds_fence();

    // ---- layer 2: y2 = silu(y1 @ w2 + b2) -> sY ----
    #pragma unroll
    for (int nt = 0; nt < 8; ++nt) acc[nt] = (f32x4){0.f, 0.f, 0.f, 0.f};
    #pragma unroll
    for (int kb = 0; kb < 4; ++kb) {
        frag8 a = *(const frag8*)&sA[(mbase + lrow) * LDA + kb * 32 + quad * 8];
        #pragma unroll
        for (int nt = 0; nt < 8; ++nt) {
            frag8 b = *(const frag8*)&w2b[(nt * 16 + lrow) * 128 + kb * 32 + quad * 8];
            acc[nt] = __builtin_amdgcn_mfma_f32_16x16x32_bf16(a, b, acc[nt], 0, 0, 0);
        }
    }
    #pragma unroll
    for (int nt = 0; nt < 8; ++nt) {
        int col = nt * 16 + lrow;
        float bias = b2[col];
        #pragma unroll
        for (int r = 0; r < 4; ++r)
            sY[(mbase + quad * 4 + r) * LDB + col] = f2b(silu_f(acc[nt][r] + bias));
    }
    lds_fence();

    // ---- coord layer: c1 = silu(y2 @ cw1 + cb1), acc stays in regs ----
    #pragma unroll
    for (int nt = 0; nt < 8; ++nt) acc[nt] = (f32x4){0.f, 0.f, 0.f, 0.f};
    #pragma unroll
    for (int kb = 0; kb < 4; ++kb) {
        frag8 a = *(const frag8*)&sY[(mbase + lrow) * LDB + kb * 32 + quad * 8];
        #pragma unroll
        for (int nt = 0; nt < 8; ++nt) {
            frag8 b = *(const frag8*)&cw1b[(nt * 16 + lrow) * 128 + kb * 32 + quad * 8];
            acc[nt] = __builtin_amdgcn_mfma_f32_16x16x32_bf16(a, b, acc[nt], 0, 0, 0);
        }
    }
    // coord epilogue: c = (c1 . cw2 + cb2)/(sqrt(n2+eps)+1); agg atomics
    {
        float part[4] = {0.f, 0.f, 0.f, 0.f};
        #pragma unroll
        for (int nt = 0; nt < 8; ++nt) {
            int col = nt * 16 + lrow;
            float bias = cb1[col];
            float w = cw2[col];
            #pragma unroll
            for (int r = 0; r < 4; ++r)
                part[r] += silu_f(acc[nt][r] + bias) * w;
        }
        #pragma unroll
        for (int off = 1; off < 16; off <<= 1) {
            #pragma unroll
            for (int r = 0; r < 4; ++r)
                part[r] += __shfl_xor(part[r], off);
        }
        if (lrow == 0) {
            int le = eb + quad;
            int p = e0 + le;
            if (p < E) {
                int node = sNode[le];
                float cb2f = cb2[0];
                #pragma unroll
                for (int r = 0; r < 4; ++r) {
                    float n2 = sNorm[le * 4 + r];
                    float c = (part[r] + cb2f) / (sqrtf(n2 + EPSF) + 1.f);
                    atomicAdd(&agg[(size_t)node * 12 + 0 + r], c * sXij[le * 12 + 0 + r]);
                    atomicAdd(&agg[(size_t)node * 12 + 4 + r], c * sXij[le * 12 + 4 + r]);
                    atomicAdd(&agg[(size_t)node * 12 + 8 + r], c * sXij[le * 12 + 8 + r]);
                }
            }
        }
    }

    // ======== the single barrier ========
    __syncthreads();

    // ---- m_i: block-wide segmented reduction over CSR-contiguous runs ----
    {
        #pragma unroll
        for (int z = 0; z < 2; ++z) {
            int elem = tid + z * 256;            // elem = t*128 + col
            int t = elem >> 7, col = elem & 127;
            float run = 0.f;
            int cur = sNode[0];
            #pragma unroll 1
            for (int le = 0; le < TE; ++le) {
                int nd = sNode[le];
                if (nd != cur) {
                    if (cur >= 0) atomicAdd(&m_i[(size_t)cur * 512 + col * 4 + t], run);
                    run = 0.f; cur = nd;
                }
                if (nd >= 0) run += b2f((unsigned)sY[(le * 4 + t) * LDB + col]);
            }
            if (cur >= 0) atomicAdd(&m_i[(size_t)cur * 512 + col * 4 + t], run);
        }
    }
}

// ---------------- node kernel: 16 nodes (64 rows), 256 threads, K=192 -> 128 -> 64 ----------------
__global__ __launch_bounds__(256, 3)
void node_kernel(const float* __restrict__ h, const float* __restrict__ m_i,
                 const unsigned short* __restrict__ nw1b,
                 const unsigned short* __restrict__ nw2b,
                 const float* __restrict__ nb1, const float* __restrict__ nb2,
                 float* __restrict__ out_h, int N)
{
    __shared__ unsigned short sA[64 * LDAN];
    __shared__ unsigned short sB[64 * LDB];

    const int tid = threadIdx.x;
    const int n0  = blockIdx.x * TN;

    if (tid < 128) {                                    // h -> k 0..63
        int ln = tid >> 3, d0 = (tid & 7) * 8;
        int node = n0 + ln;
        if (node < N) {
            const float4* hp = (const float4*)(h + (size_t)node * 256);
            float4 hv[8];
            #pragma unroll
            for (int q = 0; q < 8; ++q) hv[q] = hp[d0 + q];
            #pragma unroll
            for (int t = 0; t < 4; ++t) {
                float vv[8];
                #pragma unroll
                for (int q = 0; q < 8; ++q) vv[q] = ((const float*)&hv[q])[t];
                *(uint4*)&sA[(ln * 4 + t) * LDAN + d0] = pk8(vv);
            }
        }
    }
    for (int c = tid; c < 512; c += 256) {              // m_i -> k 64..191
        int ln = c >> 5, hd0 = (c & 31) * 4;
        int node = n0 + ln;
        if (node < N) {
            const float4* mp = (const float4*)(m_i + (size_t)node * 512);
            float4 mv[4];
            #pragma unroll
            for (int q = 0; q < 4; ++q) mv[q] = mp[hd0 + q];
            #pragma unroll
            for (int t = 0; t < 4; ++t) {
                uint2 u;
                u.x = pk2(((const float*)&mv[0])[t], ((const float*)&mv[1])[t]);
                u.y = pk2(((const float*)&mv[2])[t], ((const float*)&mv[3])[t]);
                *(uint2*)&sA[(ln * 4 + t) * LDAN + 64 + hd0] = u;
            }
        }
    }
    __syncthreads();

    const int lane = tid & 63;
    const int wave = tid >> 6;
    const int lrow = lane & 15;
    const int quad = lane >> 4;
    const int mbase = wave * 16;

    f32x4 acc[8];
    #pragma unroll
    for (int nt = 0; nt < 8; ++nt) acc[nt] = (f32x4){0.f, 0.f, 0.f, 0.f};
    #pragma unroll
    for (int kb = 0; kb < 6; ++kb) {
        frag8 a = *(const frag8*)&sA[(mbase + lrow) * LDAN + kb * 32 + quad * 8];
        #pragma unroll
        for (int nt = 0; nt < 8; ++nt) {
            frag8 b = *(const frag8*)&nw1b[(nt * 16 + lrow) * 192 + kb * 32 + quad * 8];
            acc[nt] = __builtin_amdgcn_mfma_f32_16x16x32_bf16(a, b, acc[nt], 0, 0, 0);
        }
    }
    #pragma unroll
    for (int nt = 0; nt < 8; ++nt) {
        int col = nt * 16 + lrow;
        float bias = nb1[col];
        #pragma unroll
        for (int r = 0; r < 4; ++r)
            sB[(mbase + quad * 4 + r) * LDB + col] = f2b(silu_f(acc[nt][r] + bias));
    }
    __syncthreads();

    f32x4 acc2[4];
    #pragma unroll
    for (int nt = 0; nt < 4; ++nt) acc2[nt] = (f32x4){0.f, 0.f, 0.f, 0.f};
    #pragma unroll
    for (int kb = 0; kb < 4; ++kb) {
        frag8 a = *(const frag8*)&sB[(mbase + lrow) * LDB + kb * 32 + quad * 8];
        #pragma unroll
        for (int nt = 0; nt < 4; ++nt) {
            frag8 b = *(const frag8*)&nw2b[(nt * 16 + lrow) * 128 + kb * 32 + quad * 8];
            acc2[nt] = __builtin_amdgcn_mfma_f32_16x16x32_bf16(a, b, acc2[nt], 0, 0, 0);
        }
    }
    {
        int ln = wave * 4 + quad;
        int node = n0 + ln;
        if (node < N) {
            float* op = out_h + (size_t)node * 256;
            #pragma unroll
            for (int nt = 0; nt < 4; ++nt) {
                int col = nt * 16 + lrow;
                float bias = nb2[col];
                float4 ov = { acc2[nt][0] + bias, acc2[nt][1] + bias,
                              acc2[nt][2] + bias, acc2[nt][3] + bias };
                *(float4*)&op[col * 4] = ov;
            }
        }
    }
}

// ---------------- coord update ----------------
__global__ void coord_update(const float* __restrict__ x, const float* __restrict__ agg,
                             const int* __restrict__ deg, float* __restrict__ out_x, int N)
{
    int i = blockIdx.x * 256 + threadIdx.x;
    if (i < N * 12) {
        int n = i / 12;
        out_x[i] = x[i] + agg[i] / fmaxf((float)deg[n], 1.f);
    }
}

extern "C" void kernel_launch(void* const* d_in, const int* in_sizes, int n_in,
                              void* d_out, int out_size, void* d_ws, size_t ws_size,
                              hipStream_t stream)
{
    const float* x   = (const float*)d_in[0];
    const float* h   = (const float*)d_in[1];
    const int*   ei  = (const int*)d_in[2];
    const float* ea  = (const float*)d_in[3];
    const float* w1  = (const float*)d_in[5];
    const float* b1  = (const float*)d_in[6];
    const float* w2  = (const float*)d_in[7];
    const float* b2  = (const float*)d_in[8];
    const float* cw1 = (const float*)d_in[9];
    const float* cb1 = (const float*)d_in[10];
    const float* cw2 = (const float*)d_in[11];
    const float* cb2 = (const float*)d_in[12];
    const float* nw1 = (const float*)d_in[13];
    const float* nb1 = (const float*)d_in[14];
    const float* nw2 = (const float*)d_in[15];
    const float* nb2 = (const float*)d_in[16];

    const int N = in_sizes[0] / 12;
    const int E = in_sizes[2] / 2;

    // ---- workspace layout (bytes); total ~44.5 MB ----
    char* ws = (char*)d_ws;
    unsigned short* wb = (unsigned short*)ws;              // 172032 B
    size_t o = 172032;
    int*   deg    = (int*)(ws + o);    o += (size_t)N * 4;
    int*   cursor = (int*)(ws + o);    o += (size_t)N * 4;
    float* agg    = (float*)(ws + o);  o += (size_t)N * 48;
    size_t zero_end = o;
    int*   start  = (int*)(ws + o);    o += (size_t)(N + 1) * 4;
    o = (o + 1023) & ~(size_t)1023;
    int*   list   = (int*)(ws + o);    o += (size_t)E * 4;
    o = (o + 1023) & ~(size_t)1023;
    float* m_i    = (float*)(ws + o);                      // N*512 fp32 = 41 MB

    const unsigned short* w1b  = wb;
    const unsigned short* w2b  = wb + 20480;
    const unsigned short* cw1b = wb + 36864;
    const unsigned short* nw1b = wb + 53248;
    const unsigned short* nw2b = wb + 77824;

    hipMemsetAsync(deg, 0, zero_end - 172032, stream);      // deg + cursor + agg
    hipMemsetAsync(m_i, 0, (size_t)N * 512 * sizeof(float), stream);
    prep_weights<<<336, 256, 0, stream>>>(w1, w2, cw1, nw1, nw2, wb);
    hist_kernel<<<(E + 255) / 256, 256, 0, stream>>>(ei, deg, E);
    scan_kernel<<<1, 1024, 0, stream>>>(deg, start, N);
    scatter_kernel<<<(E + 255) / 256, 256, 0, stream>>>(ei, start, cursor, list, E);

    float* out_x = (float*)d_out;
    float* out_h = out_x + (size_t)N * 12;

    edge_kernel<<<(E + TE - 1) / TE, 256, 0, stream>>>(
        x, h, ei, ea, list, w1b, w2b, cw1b, b1, b2, cb1, cb2, cw2, m_i, agg, N, E);
    node_kernel<<<(N + TN - 1) / TN, 256, 0, stream>>>(
        h, m_i, nw1b, nw2b, nb1, nb2, out_h, N);
    coord_update<<<(N * 12 + 255) / 256, 256, 0, stream>>>(x, agg, deg, out_x, N);
}